// Round 4
// baseline (24.539 us; speedup 1.0000x reference)
//
#include <hip/hip_runtime.h>
#include <hip/hip_bf16.h>

typedef short short8 __attribute__((ext_vector_type(8)));
typedef float f32x4 __attribute__((ext_vector_type(4)));

union FragAB { unsigned long long l[2]; int i[4]; short8 v; };

// Swapped-operand formulation: D[p=(b,f), j] = sum_i A[p,i] * B[i,j]
//   A[p,i] = bf16(x[b, sx, i, f])            (Xts rows, k-contiguous)
//   B[i,j] = T[j,i] = wfor[255 + diag - j + i]
//   wfor[p] = krow[p] for p<=255, 0 for 256..335 (zero-pad = triangular mask
//   AND the diagonal roll-by-one, which also switches divisor to j+1-diag).
// Four shifted copies of wfor (s = 0..3) make every lane's 8-element window
// 8-byte aligned -> B-frag = 2x ds_read_b64.
__global__ __launch_bounds__(256, 2)
void k_fused(const float* __restrict__ x,     // [16,8,256,16]
             const float* __restrict__ kern,  // [4,8,8,256]
             float* __restrict__ out)         // [16,4,8,8,256,16]
{
    __shared__ __align__(16) ushort Xts[128 * 264];     // [p][k], row 528 B
    __shared__ __align__(8)  ushort wforL[2][4][336];   // [e2][shift][q]

    const int blk = blockIdx.x;             // 0..511
    const int c  = blk & 15;                // hy chunk (2 per block)
    const int nt = (blk >> 4) & 1;          // b-half (p-half)
    const int mt = (blk >> 5) & 1;          // j-half
    const int sx = blk >> 6;
    const int t = threadIdx.x;

    // ---- build wfor shift-copies (bf16) ----
    #pragma unroll
    for (int e2 = 0; e2 < 2; ++e2) {
        const int hy = c * 2 + e2;
        const int h = hy >> 3, sy = hy & 7;
        const float* krow = kern + ((h * 8 + sx) * 8 + sy) * 256;
        #pragma unroll
        for (int s = 0; s < 4; ++s) {
            #pragma unroll
            for (int pass = 0; pass < 2; ++pass) {
                int q = t + pass * 256;
                if (q < 336) {
                    int src = q - s;
                    float v = (src >= 0 && src < 256) ? krow[src] : 0.0f;
                    __hip_bfloat16 hv = __float2bfloat16(v);
                    wforL[e2][s][q] = reinterpret_cast<ushort&>(hv);
                }
            }
        }
    }

    // ---- stage + transpose x slice -> Xts (bf16): Xts[bl*16+f][k] ----
    {
        const float4* xbase = reinterpret_cast<const float4*>(x);
        const int b0 = nt * 8;
        #pragma unroll
        for (int it = 0; it < 16; ++it) {
            int id = it * 256 + t;              // 0..4095
            int fq = id & 3;
            int k2 = (id >> 2) & 127;
            int bl = id >> 9;
            const float4* rowp = xbase + ((size_t)((b0 + bl) * 8 + sx)) * 1024;
            float4 a = rowp[(2 * k2) * 4 + fq];
            float4 cq = rowp[(2 * k2 + 1) * 4 + fq];
            #pragma unroll
            for (int e = 0; e < 4; ++e) {
                float va = (&a.x)[e], vb = (&cq.x)[e];
                __hip_bfloat16 ha = __float2bfloat16(va);
                __hip_bfloat16 hb = __float2bfloat16(vb);
                uint u = (uint)reinterpret_cast<ushort&>(ha) |
                         ((uint)reinterpret_cast<ushort&>(hb) << 16);
                int row = bl * 16 + fq * 4 + e;
                *reinterpret_cast<uint*>(reinterpret_cast<char*>(Xts) + row * 528 + k2 * 4) = u;
            }
        }
    }
    __syncthreads();

    const int lane = t & 63, wid = t >> 6;
    const int wp = wid >> 1, wj = wid & 1;      // waves: 2 over p x 2 over j
    const int laneM = lane & 15, laneG = lane >> 4;
    const int wj0 = mt * 128 + wj * 64;         // wave's j base
    const int kmax = wj0 + 64;                  // triangle skip

    const char* XtsB = reinterpret_cast<const char*>(Xts);
    const char* WB = reinterpret_cast<const char*>(wforL);
    const int abyte = (wp * 64 + laneM) * 528 + laneG * 16;

    int bB[2];
    int diagv[2];
    #pragma unroll
    for (int e2 = 0; e2 < 2; ++e2) {
        const int hy = c * 2 + e2;
        const int sy = hy & 7;
        const int diag = (sx == sy) ? 1 : 0;
        diagv[e2] = diag;
        // B element e (lane) for frag n, step kc: wfor[w00 + kc - 16n + e]
        const int w00 = 255 + diag - wj0 - laneM + 8 * laneG;
        const int s = (laneM - diag + 1) & 3;   // makes (w00+s) % 4 == 0
        bB[e2] = e2 * 2688 + s * 674 + 2 * w00; // byte base (element q = w00+s)
    }

    f32x4 acc[2][4][4];
    #pragma unroll
    for (int e2 = 0; e2 < 2; ++e2)
        #pragma unroll
        for (int m = 0; m < 4; ++m)
            #pragma unroll
            for (int n = 0; n < 4; ++n)
                acc[e2][m][n] = (f32x4){0.0f, 0.0f, 0.0f, 0.0f};

    for (int kc = 0; kc < kmax; kc += 32) {
        FragAB af[4];
        #pragma unroll
        for (int m = 0; m < 4; ++m) {
            const int4 raw = *reinterpret_cast<const int4*>(XtsB + abyte + m * 8448 + kc * 2);
            af[m].i[0] = raw.x; af[m].i[1] = raw.y;
            af[m].i[2] = raw.z; af[m].i[3] = raw.w;
        }
        #pragma unroll
        for (int e2 = 0; e2 < 2; ++e2) {
            FragAB bf[4];
            #pragma unroll
            for (int n = 0; n < 4; ++n) {
                const char* p = WB + bB[e2] + kc * 2 - 32 * n;
                bf[n].l[0] = *reinterpret_cast<const unsigned long long*>(p);
                bf[n].l[1] = *reinterpret_cast<const unsigned long long*>(p + 8);
            }
            #pragma unroll
            for (int m = 0; m < 4; ++m)
                #pragma unroll
                for (int n = 0; n < 4; ++n)
                    acc[e2][m][n] = __builtin_amdgcn_mfma_f32_16x16x32_bf16(
                        af[m].v, bf[n].v, acc[e2][m][n], 0, 0, 0);
        }
    }

    // ---- epilogue: scale rows by 1/(j+1-diag), float4 stores ----
    #pragma unroll
    for (int e2 = 0; e2 < 2; ++e2) {
        const int hy = c * 2 + e2;
        const int h = hy >> 3, sy = hy & 7;
        const int diag = diagv[e2];
        #pragma unroll
        for (int n = 0; n < 4; ++n) {
            const int j = wj0 + 16 * n + laneM;
            const int denom = j + 1 - diag;
            const float rt = (denom > 0) ? (1.0f / (float)denom) : 0.0f;
            #pragma unroll
            for (int m = 0; m < 4; ++m) {
                const int b_ = nt * 8 + wp * 4 + m;
                float* dst = out + ((((size_t)(b_ * 4 + h) * 8 + sx) * 8 + sy) * 256 + j) * 16
                             + laneG * 4;
                float4 v;
                v.x = acc[e2][m][n][0] * rt;
                v.y = acc[e2][m][n][1] * rt;
                v.z = acc[e2][m][n][2] * rt;
                v.w = acc[e2][m][n][3] * rt;
                *reinterpret_cast<float4*>(dst) = v;
            }
        }
    }
}

extern "C" void kernel_launch(void* const* d_in, const int* in_sizes, int n_in,
                              void* d_out, int out_size, void* d_ws, size_t ws_size,
                              hipStream_t stream) {
    const float* x    = (const float*)d_in[0];   // [16,8,256,16]
    const float* kern = (const float*)d_in[1];   // [4,8,8,256]
    float* out = (float*)d_out;                  // [16,4,8,8,256,16]

    k_fused<<<512, 256, 0, stream>>>(x, kern, out);
}

// Round 5
// 22.136 us; speedup vs baseline: 1.1086x; 1.1086x over previous
//
#include <hip/hip_runtime.h>
#include <hip/hip_bf16.h>

typedef short short8 __attribute__((ext_vector_type(8)));
typedef float f32x4 __attribute__((ext_vector_type(4)));

union FragAB { unsigned long long l[2]; int i[4]; short8 v; };

// Swapped-operand formulation: D[p=(b,f), j] = sum_i A[p,i] * B[i,j]
//   A[p,i] = bf16(x[b, sx, i, f])            (Xts rows, k-contiguous)
//   B[i,j] = T[j,i] = wfor[255 + diag - j + i]
//   wfor[p] = krow[p] for p<=255, 0 elsewhere (zero-pad = triangular mask AND
//   the diagonal roll-by-one, which also switches the divisor to j+1-diag).
// Four shifted copies of wfor (s = 0..3, content shifted +s) make every lane's
// 8-element window 8-byte aligned -> B-frag = 2x ds_read_b64.
//
// Scheduling: mt (j-half, which determines K-work: light kmax<=128 vs heavy
// kmax<=256) is the TOP grid bit, so under round-robin dispatch each CU hosts
// one light and one heavy block -> light blocks' stores overlap heavy blocks'
// K-loops. Within a block, each e2 tile is stored right after its K-loop to
// spread the 64 MB write burst across the kernel lifetime.
__global__ __launch_bounds__(256, 2)
void k_fused(const float* __restrict__ x,     // [16,8,256,16]
             const float* __restrict__ kern,  // [4,8,8,256]
             float* __restrict__ out)         // [16,4,8,8,256,16]
{
    __shared__ __align__(16) ushort Xts[128 * 264];     // [p][k], row 528 B
    __shared__ __align__(8)  ushort wforL[2][4][336];   // [e2][shift][q]

    const int blk = blockIdx.x;             // 0..511
    const int id = blk & 255;
    const int c  = id & 15;                 // hy chunk (2 per block)
    const int nt = (id >> 4) & 1;           // b-half (p-half)
    const int sx = id >> 5;
    const int mt = blk >> 8;                // j-half: 0 = light, 1 = heavy

    const int t = threadIdx.x;

    // ---- build wfor shift-copies (bf16) ----
    #pragma unroll
    for (int e2 = 0; e2 < 2; ++e2) {
        const int hy = c * 2 + e2;
        const int h = hy >> 3, sy = hy & 7;
        const float* krow = kern + ((h * 8 + sx) * 8 + sy) * 256;
        #pragma unroll
        for (int s = 0; s < 4; ++s) {
            #pragma unroll
            for (int pass = 0; pass < 2; ++pass) {
                int q = t + pass * 256;
                if (q < 336) {
                    int src = q - s;
                    float v = (src >= 0 && src < 256) ? krow[src] : 0.0f;
                    __hip_bfloat16 hv = __float2bfloat16(v);
                    wforL[e2][s][q] = reinterpret_cast<ushort&>(hv);
                }
            }
        }
    }

    // ---- stage + transpose x slice -> Xts (bf16): Xts[bl*16+f][k] ----
    {
        const float4* xbase = reinterpret_cast<const float4*>(x);
        const int b0 = nt * 8;
        #pragma unroll
        for (int it = 0; it < 16; ++it) {
            int id4 = it * 256 + t;             // 0..4095
            int fq = id4 & 3;
            int k2 = (id4 >> 2) & 127;
            int bl = id4 >> 9;
            const float4* rowp = xbase + ((size_t)((b0 + bl) * 8 + sx)) * 1024;
            float4 a = rowp[(2 * k2) * 4 + fq];
            float4 cq = rowp[(2 * k2 + 1) * 4 + fq];
            #pragma unroll
            for (int e = 0; e < 4; ++e) {
                float va = (&a.x)[e], vb = (&cq.x)[e];
                __hip_bfloat16 ha = __float2bfloat16(va);
                __hip_bfloat16 hb = __float2bfloat16(vb);
                uint u = (uint)reinterpret_cast<ushort&>(ha) |
                         ((uint)reinterpret_cast<ushort&>(hb) << 16);
                int row = bl * 16 + fq * 4 + e;
                *reinterpret_cast<uint*>(reinterpret_cast<char*>(Xts) + row * 528 + k2 * 4) = u;
            }
        }
    }
    __syncthreads();

    const int lane = t & 63, wid = t >> 6;
    const int wp = wid >> 1, wj = wid & 1;      // waves: 2 over p x 2 over j
    const int laneM = lane & 15, laneG = lane >> 4;
    const int wj0 = mt * 128 + wj * 64;         // wave's j base
    const int kmax = wj0 + 64;                  // triangle skip

    const char* XtsB = reinterpret_cast<const char*>(Xts);
    const char* WB = reinterpret_cast<const char*>(wforL);
    const int abyte = (wp * 64 + laneM) * 528 + laneG * 16;

    #pragma unroll
    for (int e2 = 0; e2 < 2; ++e2) {
        const int hy = c * 2 + e2;
        const int h = hy >> 3, sy = hy & 7;
        const int diag = (sx == sy) ? 1 : 0;
        // B element e (lane) for frag n, step kc: wfor[w00 + kc - 16n + e]
        const int w00 = 255 + diag - wj0 - laneM + 8 * laneG;
        const int s = (laneM - diag + 1) & 3;   // makes (w00+s) % 4 == 0
        const int bB = e2 * 2688 + s * 674 + 2 * w00;  // byte base in wforL

        f32x4 acc[4][4];
        #pragma unroll
        for (int m = 0; m < 4; ++m)
            #pragma unroll
            for (int n = 0; n < 4; ++n)
                acc[m][n] = (f32x4){0.0f, 0.0f, 0.0f, 0.0f};

        for (int kc = 0; kc < kmax; kc += 32) {
            FragAB af[4];
            #pragma unroll
            for (int m = 0; m < 4; ++m) {
                const int4 raw = *reinterpret_cast<const int4*>(XtsB + abyte + m * 8448 + kc * 2);
                af[m].i[0] = raw.x; af[m].i[1] = raw.y;
                af[m].i[2] = raw.z; af[m].i[3] = raw.w;
            }
            FragAB bf[4];
            #pragma unroll
            for (int n = 0; n < 4; ++n) {
                const char* p = WB + bB + kc * 2 - 32 * n;
                bf[n].l[0] = *reinterpret_cast<const unsigned long long*>(p);
                bf[n].l[1] = *reinterpret_cast<const unsigned long long*>(p + 8);
            }
            #pragma unroll
            for (int m = 0; m < 4; ++m)
                #pragma unroll
                for (int n = 0; n < 4; ++n)
                    acc[m][n] = __builtin_amdgcn_mfma_f32_16x16x32_bf16(
                        af[m].v, bf[n].v, acc[m][n], 0, 0, 0);
        }

        // ---- store this e2 tile now (spread the write burst) ----
        #pragma unroll
        for (int n = 0; n < 4; ++n) {
            const int j = wj0 + 16 * n + laneM;
            const int denom = j + 1 - diag;
            const float rt = (denom > 0) ? (1.0f / (float)denom) : 0.0f;
            #pragma unroll
            for (int m = 0; m < 4; ++m) {
                const int b_ = nt * 8 + wp * 4 + m;
                float* dst = out + ((((size_t)(b_ * 4 + h) * 8 + sx) * 8 + sy) * 256 + j) * 16
                             + laneG * 4;
                float4 v;
                v.x = acc[m][n][0] * rt;
                v.y = acc[m][n][1] * rt;
                v.z = acc[m][n][2] * rt;
                v.w = acc[m][n][3] * rt;
                *reinterpret_cast<float4*>(dst) = v;
            }
        }
    }
}

extern "C" void kernel_launch(void* const* d_in, const int* in_sizes, int n_in,
                              void* d_out, int out_size, void* d_ws, size_t ws_size,
                              hipStream_t stream) {
    const float* x    = (const float*)d_in[0];   // [16,8,256,16]
    const float* kern = (const float*)d_in[1];   // [4,8,8,256]
    float* out = (float*)d_out;                  // [16,4,8,8,256,16]

    k_fused<<<512, 256, 0, stream>>>(x, kern, out);
}

// Round 6
// 20.917 us; speedup vs baseline: 1.1732x; 1.0583x over previous
//
#include <hip/hip_runtime.h>
#include <hip/hip_bf16.h>

typedef short short8 __attribute__((ext_vector_type(8)));
typedef float f32x4 __attribute__((ext_vector_type(4)));

union FragAB { unsigned long long l[2]; int i[4]; short8 v; };

// Swapped-operand formulation: D[p=(b,f), j] = sum_i A[p,i] * B[i,j]
//   A[p,i] = bf16(x[b, sx, i, f])            (Xts rows, k-contiguous)
//   B[i,j] = T[j,i] = wfor[255 + diag - j + i]
//   wfor[q] = krow[q] for q<=255, 0 elsewhere (zero-pad = triangular mask AND
//   the diagonal roll-by-one, which also switches the divisor to j+1-diag).
// Four shifted copies of wfor (copy s holds wfor shifted +s) make every lane's
// 8-element window 8-byte aligned -> B-frag = 2x ds_read_b64.
//
// Round-6 structure: block = (hy, sx, nt) computes a 64p x 256j tile; the 4
// waves take the 4 j-bands (kmax = 64*(wid+1)), so every block has identical
// total K-work (20 wave-K-steps) -> perfect CU balance, and light waves'
// stores drain while heavy waves still compute. LDS 37.5 KB + lb(256,3)
// -> 12 waves/CU (vs 8 in round 5) for latency hiding.
__global__ __launch_bounds__(256, 3)
void k_fused(const float* __restrict__ x,     // [16,8,256,16]
             const float* __restrict__ kern,  // [4,8,8,256]
             float* __restrict__ out)         // [16,4,8,8,256,16]
{
    __shared__ __align__(16) ushort Xts[64 * 264];   // [p][k], row 528 B
    __shared__ __align__(8)  ushort wforL[4][336];   // [shift][q]
    __shared__ float rtab[256];

    const int blk = blockIdx.x;             // 0..1023
    const int hy = blk & 31;                // h*8 + sy
    const int sx = (blk >> 5) & 7;
    const int nt = blk >> 8;                // p-quarter (b-quad)
    const int h = hy >> 3, sy = hy & 7;
    const int diag = (sx == sy) ? 1 : 0;
    const int t = threadIdx.x;

    // ---- wfor shift-copies (bf16) ----
    {
        const float* krow = kern + ((h * 8 + sx) * 8 + sy) * 256;
        #pragma unroll
        for (int s = 0; s < 4; ++s) {
            #pragma unroll
            for (int pass = 0; pass < 2; ++pass) {
                int q = t + pass * 256;
                if (q < 336) {
                    int src = q - s;
                    float v = (src >= 0 && src < 256) ? krow[src] : 0.0f;
                    __hip_bfloat16 hv = __float2bfloat16(v);
                    wforL[s][q] = reinterpret_cast<ushort&>(hv);
                }
            }
        }
    }
    // ---- reciprocal table for this block's diag ----
    {
        int denom = t + 1 - diag;
        rtab[t] = (denom > 0) ? (1.0f / (float)denom) : 0.0f;
    }
    // ---- stage + transpose x quarter-slice -> Xts: Xts[bl*16+f][k] ----
    {
        const float4* xbase = reinterpret_cast<const float4*>(x);
        #pragma unroll
        for (int it = 0; it < 8; ++it) {
            int id = it * 256 + t;              // 0..2047 (k2-pair units)
            int fq = id & 3;
            int k2 = (id >> 2) & 127;
            int bl = id >> 9;                   // local b 0..3
            const float4* rowp = xbase + ((size_t)((nt * 4 + bl) * 8 + sx)) * 1024;
            float4 a = rowp[(2 * k2) * 4 + fq];
            float4 cq = rowp[(2 * k2 + 1) * 4 + fq];
            #pragma unroll
            for (int e = 0; e < 4; ++e) {
                float va = (&a.x)[e], vb = (&cq.x)[e];
                __hip_bfloat16 ha = __float2bfloat16(va);
                __hip_bfloat16 hb = __float2bfloat16(vb);
                uint u = (uint)reinterpret_cast<ushort&>(ha) |
                         ((uint)reinterpret_cast<ushort&>(hb) << 16);
                int row = bl * 16 + fq * 4 + e;
                *reinterpret_cast<uint*>(reinterpret_cast<char*>(Xts) + row * 528 + k2 * 4) = u;
            }
        }
    }
    __syncthreads();

    const int lane = t & 63, wid = t >> 6;
    const int laneM = lane & 15, laneG = lane >> 4;
    const int wj0 = wid * 64;                   // wave's j base
    const int kmax = wj0 + 64;                  // triangle skip

    const char* XtsB = reinterpret_cast<const char*>(Xts);
    const char* WB = reinterpret_cast<const char*>(wforL);
    const int abyte = laneM * 528 + laneG * 16;

    // B element e (lane) for frag n, step kc: wfor[w00 + kc - 16n + e]
    const int w00 = 255 + diag - wj0 - laneM + 8 * laneG;
    const int s = (laneM - diag + 1) & 3;       // makes (w00+s) % 4 == 0
    const int bB = s * 674 + 2 * w00;           // byte base (incl. +s shift)

    f32x4 acc[4][4];
    #pragma unroll
    for (int m = 0; m < 4; ++m)
        #pragma unroll
        for (int n = 0; n < 4; ++n)
            acc[m][n] = (f32x4){0.0f, 0.0f, 0.0f, 0.0f};

    for (int kc = 0; kc < kmax; kc += 32) {
        FragAB af[4];
        #pragma unroll
        for (int m = 0; m < 4; ++m) {
            const int4 raw = *reinterpret_cast<const int4*>(XtsB + abyte + m * 8448 + kc * 2);
            af[m].i[0] = raw.x; af[m].i[1] = raw.y;
            af[m].i[2] = raw.z; af[m].i[3] = raw.w;
        }
        FragAB bf[4];
        #pragma unroll
        for (int n = 0; n < 4; ++n) {
            const char* p = WB + bB + kc * 2 - 32 * n;
            bf[n].l[0] = *reinterpret_cast<const unsigned long long*>(p);
            bf[n].l[1] = *reinterpret_cast<const unsigned long long*>(p + 8);
        }
        #pragma unroll
        for (int m = 0; m < 4; ++m)
            #pragma unroll
            for (int n = 0; n < 4; ++n)
                acc[m][n] = __builtin_amdgcn_mfma_f32_16x16x32_bf16(
                    af[m].v, bf[n].v, acc[m][n], 0, 0, 0);
    }

    // ---- epilogue: scale rows, float4 stores; m outer / n inner so each m
    // emits a 4 KB-contiguous run over n ----
    #pragma unroll
    for (int m = 0; m < 4; ++m) {
        const int b_ = nt * 4 + m;
        float* obase = out + (((size_t)(b_ * 4 + h) * 8 + sx) * 8 + sy) * 4096
                       + laneG * 4;
        #pragma unroll
        for (int n = 0; n < 4; ++n) {
            const int j = wj0 + 16 * n + laneM;
            const float rt = rtab[j];
            float4 v;
            v.x = acc[m][n][0] * rt;
            v.y = acc[m][n][1] * rt;
            v.z = acc[m][n][2] * rt;
            v.w = acc[m][n][3] * rt;
            *reinterpret_cast<float4*>(obase + (size_t)j * 16) = v;
        }
    }
}

extern "C" void kernel_launch(void* const* d_in, const int* in_sizes, int n_in,
                              void* d_out, int out_size, void* d_ws, size_t ws_size,
                              hipStream_t stream) {
    const float* x    = (const float*)d_in[0];   // [16,8,256,16]
    const float* kern = (const float*)d_in[1];   // [4,8,8,256]
    float* out = (float*)d_out;                  // [16,4,8,8,256,16]

    k_fused<<<1024, 256, 0, stream>>>(x, kern, out);
}